// Round 3
// baseline (671.955 us; speedup 1.0000x reference)
//
#include <hip/hip_runtime.h>

#define T_ 512
#define K_ 128
#define B_ 256

// X-macro over the 8 groups of 4 transition-table registers.
#define GROUPS(F) F(0) F(1) F(2) F(3) F(4) F(5) F(6) F(7)

// One block per batch, 1024 threads = 16 waves.
// Waves 0-7:  forward (factored logsumexp), j = lin>>2, c = lin&3 (i-quarter)
// Waves 8-15: viterbi (max/argmax), same mapping.
//
// Round-1/2 failure: per-thread table as a C array was never register-allocated
// (VGPR_Count 36/56) — compiler sank the 32 loop-invariant transition loads into
// the t-loop -> ~12.5 TB of L1/L2 traffic, L2-bound at ~600 us. Fix: 32 NAMED
// scalars + asm-volatile register fence (opaque to remat/sinking).
//
// Normalization: lagged scalar S_t = alpha_{t-1}(j=0) (2-slot LDS), no per-step
// cross-wave max reduce. exp args bounded by ~e^35 -> fp32-safe.
__global__ __launch_bounds__(1024, 4) void crf_main(
    const float* __restrict__ emissions,
    const int* __restrict__ tag_ids,
    const int* __restrict__ lengths,
    const float* __restrict__ transitions,
    float* __restrict__ out,
    float* __restrict__ ws_ll,
    int* __restrict__ ws_cnt)
{
    __shared__ unsigned char bpLDS[T_ * K_];            // 64 KB backpointers
    __shared__ __align__(16) float eaBuf[2][K_];        // exp(alpha - S), double buffered
    __shared__ __align__(16) float vaBuf[2][K_];        // viterbi scores, double buffered
    __shared__ float sNorm[2];                          // lagged normalizer alpha_t(0)
    __shared__ float redLDS[8];                         // score partials (live through loop)
    __shared__ int   redILDS[8];                        // accuracy-count partials
    __shared__ unsigned char decLDS[T_];                // decoded chain
    __shared__ int ltagLDS;

    const int b   = blockIdx.x;
    const int tid = threadIdx.x;
    const int len = lengths[b];
    const float* emB = emissions + (size_t)b * T_ * K_;
    const int*  tagB = tag_ids + b * T_;

    // ---------------- sequence score (unary + binary), one t per thread ----------------
    if (tid < T_) {
        int t = tid;
        float s = 0.f;
        if (t < len) {
            int tg = tagB[t];
            s = emB[t * K_ + tg];
            if (t >= 1) s += transitions[tagB[t - 1] * K_ + tg];
        }
        #pragma unroll
        for (int m = 1; m < 64; m <<= 1) s += __shfl_xor(s, m);
        if ((tid & 63) == 0) redLDS[tid >> 6] = s;
    }

    const int role = tid >> 9;          // 0 = forward, 1 = viterbi
    const int lin  = tid & 511;
    const int j = lin >> 2;             // column 0..127
    const int c = lin & 3;              // quarter of the i-range

    // ---------------- per-thread transition slice: 32 NAMED registers ----------------
#define DECLW(g) float w##g##0, w##g##1, w##g##2, w##g##3;
    GROUPS(DECLW)
    {
        const float* wp = transitions + (c * 32) * K_ + j;
#define LOADW(g) w##g##0 = wp[(4*g+0)*K_]; w##g##1 = wp[(4*g+1)*K_]; \
                 w##g##2 = wp[(4*g+2)*K_]; w##g##3 = wp[(4*g+3)*K_];
        GROUPS(LOADW)
        if (role == 0) {
#define EXPW(g) w##g##0 = __expf(w##g##0); w##g##1 = __expf(w##g##1); \
                w##g##2 = __expf(w##g##2); w##g##3 = __expf(w##g##3);
            GROUPS(EXPW)
        }
        // Register fence: forces materialization before the loop, blocks remat.
#define FENCEW(g) asm volatile("" : "+v"(w##g##0), "+v"(w##g##1), "+v"(w##g##2), "+v"(w##g##3));
        GROUPS(FENCEW)
    }

    // ---------------- init t = 0 ----------------
    float e0 = emB[j];
    if (role == 0) {
        if (c == 0) eaBuf[0][j] = __expf(e0);           // offset S(buf0) = 0
        if (lin == 0) sNorm[0] = e0;                    // alpha_0(0)
    } else {
        if (c == 0) vaBuf[0][j] = e0;
    }
    float emNext = emB[K_ + j];                         // prefetch t = 1
    __syncthreads();

    // ---------------- main recurrence ----------------
    int cur = 0;
    float Sprev = 0.f;                                  // offset of eaBuf[cur]
    for (int t = 1; t < len; ++t) {
        float emit = emNext;
        { int tn = (t + 1 < T_) ? (t + 1) : (T_ - 1);   // prefetch next step early
          emNext = emB[tn * K_ + j]; }
        if (role == 0) {
            float Scur = sNorm[cur];                    // alpha_{t-1}(0): offset for new buf
            const float* ea = &eaBuf[cur][c * 32];
            float a0 = 0.f, a1 = 0.f, a2 = 0.f, a3 = 0.f;
#define DOTW(g) { float4 e4 = *(const float4*)(ea + 4*g); \
                  a0 = fmaf(e4.x, w##g##0, a0); a1 = fmaf(e4.y, w##g##1, a1); \
                  a2 = fmaf(e4.z, w##g##2, a2); a3 = fmaf(e4.w, w##g##3, a3); }
            GROUPS(DOTW)
            float dot = (a0 + a1) + (a2 + a3);
            dot += __shfl_xor(dot, 1);                  // combine the four i-quarters
            dot += __shfl_xor(dot, 2);
            float anew = __logf(dot) + Sprev + emit;
            if (c == 0) eaBuf[cur ^ 1][j] = __expf(anew - Scur);
            if (lin == 0) sNorm[cur ^ 1] = anew;        // j==0 value becomes next offset
            Sprev = Scur;
        } else {
            const float* va = &vaBuf[cur][c * 32];
            float mB = -3.4028235e38f;
            int arg = 0;
#define VITW(g) { float4 v4 = *(const float4*)(va + 4*g); \
        float s0 = v4.x + w##g##0; if (s0 > mB) { mB = s0; arg = 4*g+0; } \
        float s1 = v4.y + w##g##1; if (s1 > mB) { mB = s1; arg = 4*g+1; } \
        float s2 = v4.z + w##g##2; if (s2 > mB) { mB = s2; arg = 4*g+2; } \
        float s3 = v4.w + w##g##3; if (s3 > mB) { mB = s3; arg = 4*g+3; } }
            GROUPS(VITW)                                // ascending i = first-max-wins
            arg += c * 32;
            #pragma unroll
            for (int d = 1; d < 4; d <<= 1) {           // quad lexicographic (max val, min idx)
                float om = __shfl_xor(mB, d);
                int   oa = __shfl_xor(arg, d);
                if (om > mB || (om == mB && oa < arg)) { mB = om; arg = oa; }
            }
            if (c == 0) {
                vaBuf[cur ^ 1][j] = mB + emit;
                bpLDS[t * K_ + j] = (unsigned char)arg;
            }
        }
        cur ^= 1;
        __syncthreads();
    }

    // ---------------- logZ (fwd lanes tid<64 hold uniform Sprev) ----------------
    float logZv = 0.f;
    if (tid < 64) {
        float s = eaBuf[cur][tid] + eaBuf[cur][tid + 64];
        #pragma unroll
        for (int m = 1; m < 64; m <<= 1) s += __shfl_xor(s, m);
        logZv = Sprev + __logf(s);                      // valid in lane 0 (tid 0)
    }

    // ---------------- last tag: argmax_j v_final (first-max-wins) ----------------
    if (tid >= 512 && tid < 576) {
        int l = tid - 512;
        float m = vaBuf[cur][l]; int a = l;
        float v2 = vaBuf[cur][l + 64];
        if (v2 > m) { m = v2; a = l + 64; }
        #pragma unroll
        for (int sft = 1; sft < 64; sft <<= 1) {
            float om = __shfl_xor(m, sft);
            int   oa = __shfl_xor(a, sft);
            if (om > m || (om == m && oa < a)) { m = om; a = oa; }
        }
        if (l == 0) ltagLDS = a;
    }
    __syncthreads();

    // ---------------- backtrace (serial chain through LDS) ----------------
    if (tid == 0) {
        int tg = ltagLDS;
        for (int t = T_ - 1; t >= 1; --t) {
            decLDS[t] = (unsigned char)tg;
            if (t < len) tg = bpLDS[t * K_ + tg];       // identity bp for t >= len
        }
        decLDS[0] = (unsigned char)tg;
    }
    __syncthreads();

    // ---------------- decoded write + accuracy count ----------------
    if (tid < T_) {
        int t = tid;
        int dv = decLDS[t];
        out[1 + b * T_ + t] = (float)dv;
        int good = (t < len && tagB[t] == dv) ? 1 : 0;
        #pragma unroll
        for (int m = 1; m < 64; m <<= 1) good += __shfl_xor(good, m);
        if ((tid & 63) == 0) redILDS[tid >> 6] = good;
    }
    __syncthreads();

    if (tid == 0) {
        float sc = 0.f; int cnt = 0;
        #pragma unroll
        for (int w = 0; w < 8; ++w) { sc += redLDS[w]; cnt += redILDS[w]; }
        ws_ll[b]  = sc - logZv;                         // log-likelihood of batch b
        ws_cnt[b] = cnt;
    }
}

// Final reduction: loss = -mean(ll), accuracy = sum(correct)/sum(len)
__global__ void crf_final(const float* __restrict__ ws_ll,
                          const int* __restrict__ ws_cnt,
                          const int* __restrict__ lengths,
                          float* __restrict__ out)
{
    __shared__ float sll[4];
    __shared__ int scnt[4], slen[4];
    int tid = threadIdx.x;                              // blockDim == B_ == 256
    float ll = ws_ll[tid];
    int   cn = ws_cnt[tid];
    int   L  = lengths[tid];
    #pragma unroll
    for (int m = 1; m < 64; m <<= 1) {
        ll += __shfl_xor(ll, m);
        cn += __shfl_xor(cn, m);
        L  += __shfl_xor(L, m);
    }
    if ((tid & 63) == 0) { sll[tid >> 6] = ll; scnt[tid >> 6] = cn; slen[tid >> 6] = L; }
    __syncthreads();
    if (tid == 0) {
        float llS = sll[0] + sll[1] + sll[2] + sll[3];
        int   cS  = scnt[0] + scnt[1] + scnt[2] + scnt[3];
        int   LS  = slen[0] + slen[1] + slen[2] + slen[3];
        out[0] = -llS / (float)B_;
        out[1 + B_ * T_] = (float)cS / (float)LS;
    }
}

extern "C" void kernel_launch(void* const* d_in, const int* in_sizes, int n_in,
                              void* d_out, int out_size, void* d_ws, size_t ws_size,
                              hipStream_t stream) {
    const float* emissions   = (const float*)d_in[0];
    const int*   tag_ids     = (const int*)d_in[1];
    const int*   lengths     = (const int*)d_in[2];
    const float* transitions = (const float*)d_in[3];
    float* out = (float*)d_out;

    float* ws_ll  = (float*)d_ws;
    int*   ws_cnt = (int*)((char*)d_ws + B_ * sizeof(float));

    crf_main<<<B_, 1024, 0, stream>>>(emissions, tag_ids, lengths, transitions,
                                      out, ws_ll, ws_cnt);
    crf_final<<<1, B_, 0, stream>>>(ws_ll, ws_cnt, lengths, out);
}

// Round 4
// 648.387 us; speedup vs baseline: 1.0363x; 1.0363x over previous
//
#include <hip/hip_runtime.h>

#define T_ 512
#define K_ 128
#define B_ 256

// Padded layout: i-quarter q (32 floats) starts at 36*q -> element i at i + 4*(i>>5).
// Quarter bases hit LDS banks {0,4,8,12}, so the 4 c-group float4 reads per wave
// are bank-disjoint (rounds 1-3 were 4-way conflicted: quarter stride 128B == bank-
// aliased; SQ_LDS_BANK_CONFLICT 3.09e7 const, LDS pipe ~2400cyc/step = bottleneck).
// 144-float rows keep every float4 16B-aligned (36 floats = 144B = 9x16B).
#define PIDX(i) ((i) + (((i) >> 5) << 2))

#define GROUPS(F) F(0) F(1) F(2) F(3) F(4) F(5) F(6) F(7)

// One block per batch, 1024 threads = 16 waves.
// Waves 0-7:  forward (factored logsumexp), j = lin>>2, c = lin&3 (i-quarter)
// Waves 8-15: viterbi (max/argmax), same mapping.
// Lagged normalizer S_t = alpha_{t-1}(j=0) (2-slot LDS); exp args fp32-safe.
__global__ __launch_bounds__(1024, 4) void crf_main(
    const float* __restrict__ emissions,
    const int* __restrict__ tag_ids,
    const int* __restrict__ lengths,
    const float* __restrict__ transitions,
    float* __restrict__ out,
    float* __restrict__ ws_ll,
    int* __restrict__ ws_cnt)
{
    __shared__ unsigned char bpLDS[T_ * K_];            // 64 KB backpointers
    __shared__ __align__(16) float eaBuf[2][144];       // exp(alpha - S), padded, dbuf
    __shared__ __align__(16) float vaBuf[2][144];       // viterbi scores, padded, dbuf
    __shared__ float sNorm[2];                          // lagged normalizer alpha_t(0)
    __shared__ float redLDS[8];                         // score partials (live through loop)
    __shared__ int   redILDS[8];                        // accuracy-count partials
    __shared__ unsigned char decLDS[T_];                // decoded chain
    __shared__ int ltagLDS;

    const int b   = blockIdx.x;
    const int tid = threadIdx.x;
    const int len = lengths[b];
    const float* emB = emissions + (size_t)b * T_ * K_;
    const int*  tagB = tag_ids + b * T_;

    // ---------------- sequence score (unary + binary), one t per thread ----------------
    if (tid < T_) {
        int t = tid;
        float s = 0.f;
        if (t < len) {
            int tg = tagB[t];
            s = emB[t * K_ + tg];
            if (t >= 1) s += transitions[tagB[t - 1] * K_ + tg];
        }
        #pragma unroll
        for (int m = 1; m < 64; m <<= 1) s += __shfl_xor(s, m);
        if ((tid & 63) == 0) redLDS[tid >> 6] = s;
    }

    const int role = tid >> 9;          // 0 = forward, 1 = viterbi
    const int lin  = tid & 511;
    const int j = lin >> 2;             // column 0..127
    const int c = lin & 3;              // quarter of the i-range

    // ---------------- per-thread transition slice: 32 NAMED registers ----------------
#define DECLW(g) float w##g##0, w##g##1, w##g##2, w##g##3;
    GROUPS(DECLW)
    {
        const float* wp = transitions + (c * 32) * K_ + j;
#define LOADW(g) w##g##0 = wp[(4*g+0)*K_]; w##g##1 = wp[(4*g+1)*K_]; \
                 w##g##2 = wp[(4*g+2)*K_]; w##g##3 = wp[(4*g+3)*K_];
        GROUPS(LOADW)
        if (role == 0) {
#define EXPW(g) w##g##0 = __expf(w##g##0); w##g##1 = __expf(w##g##1); \
                w##g##2 = __expf(w##g##2); w##g##3 = __expf(w##g##3);
            GROUPS(EXPW)
        }
#define FENCEW(g) asm volatile("" : "+v"(w##g##0), "+v"(w##g##1), "+v"(w##g##2), "+v"(w##g##3));
        GROUPS(FENCEW)
    }

    // ---------------- init t = 0 ----------------
    float e0 = emB[j];
    if (role == 0) {
        if (c == 0) eaBuf[0][PIDX(j)] = __expf(e0);     // offset S(buf0) = 0
        if (lin == 0) sNorm[0] = e0;                    // alpha_0(0)
    } else {
        if (c == 0) vaBuf[0][PIDX(j)] = e0;
    }
    float emNext = emB[K_ + j];                         // prefetch t = 1
    __syncthreads();

    // ---------------- main recurrence ----------------
    int cur = 0;
    float Sprev = 0.f;                                  // offset of eaBuf[cur]
    for (int t = 1; t < len; ++t) {
        float emit = emNext;
        { int tn = (t + 1 < T_) ? (t + 1) : (T_ - 1);   // prefetch next step early
          emNext = emB[tn * K_ + j]; }
        if (role == 0) {
            float Scur = sNorm[cur];                    // alpha_{t-1}(0): offset for new buf
            const float* ea = &eaBuf[cur][c * 36];
            float a0 = 0.f, a1 = 0.f, a2 = 0.f, a3 = 0.f;
#define DOTW(g) { float4 e4 = *(const float4*)(ea + 4*g); \
                  a0 = fmaf(e4.x, w##g##0, a0); a1 = fmaf(e4.y, w##g##1, a1); \
                  a2 = fmaf(e4.z, w##g##2, a2); a3 = fmaf(e4.w, w##g##3, a3); }
            GROUPS(DOTW)
            float dot = (a0 + a1) + (a2 + a3);
            dot += __shfl_xor(dot, 1);                  // combine the four i-quarters
            dot += __shfl_xor(dot, 2);
            float anew = __logf(dot) + Sprev + emit;
            if (c == 0) eaBuf[cur ^ 1][PIDX(j)] = __expf(anew - Scur);
            if (lin == 0) sNorm[cur ^ 1] = anew;        // j==0 value becomes next offset
            Sprev = Scur;
        } else {
            const float* va = &vaBuf[cur][c * 36];
            // 4 independent (max,arg) accumulators over blocked k-ranges:
            // shorter dep chain; strict-> combine preserves first-max-wins.
            float m0 = -3.4028235e38f, m1 = m0, m2 = m0, m3 = m0;
            int a0 = 0, a1 = 0, a2 = 0, a3 = 0;
#define VITW(g, mm, aa) { float4 v4 = *(const float4*)(va + 4*g); \
        float s0 = v4.x + w##g##0; if (s0 > mm) { mm = s0; aa = 4*g+0; } \
        float s1 = v4.y + w##g##1; if (s1 > mm) { mm = s1; aa = 4*g+1; } \
        float s2 = v4.z + w##g##2; if (s2 > mm) { mm = s2; aa = 4*g+2; } \
        float s3 = v4.w + w##g##3; if (s3 > mm) { mm = s3; aa = 4*g+3; } }
            VITW(0, m0, a0) VITW(1, m0, a0)
            VITW(2, m1, a1) VITW(3, m1, a1)
            VITW(4, m2, a2) VITW(5, m2, a2)
            VITW(6, m3, a3) VITW(7, m3, a3)
            if (m1 > m0) { m0 = m1; a0 = a1; }          // higher-k block loses ties
            if (m3 > m2) { m2 = m3; a2 = a3; }
            if (m2 > m0) { m0 = m2; a0 = a2; }
            int arg = a0 + c * 32;
            float mB = m0;
            #pragma unroll
            for (int d = 1; d < 4; d <<= 1) {           // quad lexicographic (max val, min idx)
                float om = __shfl_xor(mB, d);
                int   oa = __shfl_xor(arg, d);
                if (om > mB || (om == mB && oa < arg)) { mB = om; arg = oa; }
            }
            if (c == 0) {
                vaBuf[cur ^ 1][PIDX(j)] = mB + emit;
                bpLDS[t * K_ + j] = (unsigned char)arg;
            }
        }
        cur ^= 1;
        __syncthreads();
    }

    // ---------------- logZ (fwd lanes tid<64 hold uniform Sprev) ----------------
    float logZv = 0.f;
    if (tid < 64) {
        float s = eaBuf[cur][PIDX(tid)] + eaBuf[cur][PIDX(tid + 64)];
        #pragma unroll
        for (int m = 1; m < 64; m <<= 1) s += __shfl_xor(s, m);
        logZv = Sprev + __logf(s);                      // valid in lane 0 (tid 0)
    }

    // ---------------- last tag: argmax_j v_final (first-max-wins) ----------------
    if (tid >= 512 && tid < 576) {
        int l = tid - 512;
        float m = vaBuf[cur][PIDX(l)]; int a = l;
        float v2 = vaBuf[cur][PIDX(l + 64)];
        if (v2 > m) { m = v2; a = l + 64; }
        #pragma unroll
        for (int sft = 1; sft < 64; sft <<= 1) {
            float om = __shfl_xor(m, sft);
            int   oa = __shfl_xor(a, sft);
            if (om > m || (om == m && oa < a)) { m = om; a = oa; }
        }
        if (l == 0) ltagLDS = a;
    }
    __syncthreads();

    // ---------------- backtrace (serial chain through LDS) ----------------
    if (tid == 0) {
        int tg = ltagLDS;
        for (int t = T_ - 1; t >= 1; --t) {
            decLDS[t] = (unsigned char)tg;
            if (t < len) tg = bpLDS[t * K_ + tg];       // identity bp for t >= len
        }
        decLDS[0] = (unsigned char)tg;
    }
    __syncthreads();

    // ---------------- decoded write + accuracy count ----------------
    if (tid < T_) {
        int t = tid;
        int dv = decLDS[t];
        out[1 + b * T_ + t] = (float)dv;
        int good = (t < len && tagB[t] == dv) ? 1 : 0;
        #pragma unroll
        for (int m = 1; m < 64; m <<= 1) good += __shfl_xor(good, m);
        if ((tid & 63) == 0) redILDS[tid >> 6] = good;
    }
    __syncthreads();

    if (tid == 0) {
        float sc = 0.f; int cnt = 0;
        #pragma unroll
        for (int w = 0; w < 8; ++w) { sc += redLDS[w]; cnt += redILDS[w]; }
        ws_ll[b]  = sc - logZv;                         // log-likelihood of batch b
        ws_cnt[b] = cnt;
    }
}

// Final reduction: loss = -mean(ll), accuracy = sum(correct)/sum(len)
__global__ void crf_final(const float* __restrict__ ws_ll,
                          const int* __restrict__ ws_cnt,
                          const int* __restrict__ lengths,
                          float* __restrict__ out)
{
    __shared__ float sll[4];
    __shared__ int scnt[4], slen[4];
    int tid = threadIdx.x;                              // blockDim == B_ == 256
    float ll = ws_ll[tid];
    int   cn = ws_cnt[tid];
    int   L  = lengths[tid];
    #pragma unroll
    for (int m = 1; m < 64; m <<= 1) {
        ll += __shfl_xor(ll, m);
        cn += __shfl_xor(cn, m);
        L  += __shfl_xor(L, m);
    }
    if ((tid & 63) == 0) { sll[tid >> 6] = ll; scnt[tid >> 6] = cn; slen[tid >> 6] = L; }
    __syncthreads();
    if (tid == 0) {
        float llS = sll[0] + sll[1] + sll[2] + sll[3];
        int   cS  = scnt[0] + scnt[1] + scnt[2] + scnt[3];
        int   LS  = slen[0] + slen[1] + slen[2] + slen[3];
        out[0] = -llS / (float)B_;
        out[1 + B_ * T_] = (float)cS / (float)LS;
    }
}

extern "C" void kernel_launch(void* const* d_in, const int* in_sizes, int n_in,
                              void* d_out, int out_size, void* d_ws, size_t ws_size,
                              hipStream_t stream) {
    const float* emissions   = (const float*)d_in[0];
    const int*   tag_ids     = (const int*)d_in[1];
    const int*   lengths     = (const int*)d_in[2];
    const float* transitions = (const float*)d_in[3];
    float* out = (float*)d_out;

    float* ws_ll  = (float*)d_ws;
    int*   ws_cnt = (int*)((char*)d_ws + B_ * sizeof(float));

    crf_main<<<B_, 1024, 0, stream>>>(emissions, tag_ids, lengths, transitions,
                                      out, ws_ll, ws_cnt);
    crf_final<<<1, B_, 0, stream>>>(ws_ll, ws_cnt, lengths, out);
}